// Round 2
// baseline (192.255 us; speedup 1.0000x reference)
//
#include <hip/hip_runtime.h>

#define NN 500
#define SLOPEC 0.01f
#define NBLK 256          // grid size == CU count: 1 block/CU ALWAYS fits -> all
                          // blocks co-resident unconditionally -> barrier safe.

typedef unsigned short us;
typedef unsigned int u32;
typedef unsigned long long u64;

// ---- canonical fp32 copies of all inputs + scratch, as device globals ----
// (16B-aligned by construction: safe for float4 loads. Harness input buffers
//  are NOT guaranteed 16B-aligned — inputs only ever read with scalar loads.)
__device__ __align__(16) float g_imf[16000];
__device__ __align__(16) float g_c[1504];
__device__ __align__(16) float g_ct[1504];
__device__ __align__(16) float g_wc1[2048];
__device__ __align__(16) float g_bc1[64];
__device__ __align__(16) float g_wc2[8192];
__device__ __align__(16) float g_bc2[128];
__device__ __align__(16) float g_wps1[32768];
__device__ __align__(16) float g_bps1[256];
__device__ __align__(16) float g_wps2[32768];
__device__ __align__(16) float g_bps2[128];
__device__ __align__(16) float g_wp1[192];
__device__ __align__(16) float g_bp1[64];
__device__ __align__(16) float g_wp2[8192];
__device__ __align__(16) float g_bp2[128];
__device__ __align__(16) float g_wfc1[16384];
__device__ __align__(16) float g_bfc1[64];
__device__ __align__(16) float g_wfc2[10240];
__device__ __align__(16) float g_bfc2[64];
__device__ __align__(16) float g_wfc[8192];
__device__ __align__(16) float g_bfc[64];

__device__ __align__(16) float g_cfw[NN*128];
__device__ __align__(16) float g_Yw[NN*128];
__device__ __align__(16) float g_Zw[NN*128];
__device__ __align__(16) float g_logA[4000];   // exp(-dist) numerators
__device__ __align__(16) float g_logB[4000];
__device__ int   g_inds[4000];
__device__ int   g_inds_tc[4000];
__device__ float g_sumA;                       // softmax denominators (atomic)
__device__ float g_sumB;

// grid barrier state: cnt returns to 0 after each barrier, gen grows
// monotonically -> correct across graph replays without host-side reset.
__device__ int g_bar_cnt = 0;
__device__ int g_bar_gen = 0;

__device__ __forceinline__ float b2f(us u){ return __uint_as_float(((u32)u)<<16); }
__device__ __forceinline__ us f2b(float f){
  u32 u = __float_as_uint(f);
  u32 r = u + 0x7fffu + ((u>>16)&1u);
  return (us)(r>>16);
}
__device__ __forceinline__ float lrelu(float x){ return x >= 0.f ? x : SLOPEC*x; }
__device__ __forceinline__ float dot4(const float4 w, const float* h){
  return w.x*h[0] + w.y*h[1] + w.z*h[2] + w.w*h[3];
}
__device__ __forceinline__ int clampi(int v){ return v < 0 ? 0 : (v >= NN ? NN-1 : v); }

// Device-scope grid barrier. Safe because NBLK==256 blocks of 256 thr / ~6KB LDS
// are unconditionally co-resident on 256 CUs (1 block/CU worst case).
__device__ __forceinline__ void grid_barrier(){
  __syncthreads();
  if (threadIdx.x == 0){
    __threadfence();   // release: make this block's writes device-visible
    int gen = __hip_atomic_load(&g_bar_gen, __ATOMIC_RELAXED, __HIP_MEMORY_SCOPE_AGENT);
    int prev = __hip_atomic_fetch_add(&g_bar_cnt, 1, __ATOMIC_ACQ_REL, __HIP_MEMORY_SCOPE_AGENT);
    if (prev == NBLK-1){
      __hip_atomic_store(&g_bar_cnt, 0, __ATOMIC_RELAXED, __HIP_MEMORY_SCOPE_AGENT);
      __hip_atomic_fetch_add(&g_bar_gen, 1, __ATOMIC_RELEASE, __HIP_MEMORY_SCOPE_AGENT);
    } else {
      while (__hip_atomic_load(&g_bar_gen, __ATOMIC_RELAXED, __HIP_MEMORY_SCOPE_AGENT) == gen)
        __builtin_amdgcn_s_sleep(2);
    }
    __threadfence();   // acquire: invalidate caches before reading others' data
  }
  __syncthreads();
}

// ONE persistent kernel, 256 blocks, grid-stride over work items per phase:
//   phase 0: dtype-detect + convert all inputs to fp32 device globals
//   barrier
//   phase 1: items 0..249   = KNN (4 queries/item) + exp numerators + atomic denom
//            items 250..499 = per-point conv chains, TWO points per item
//   barrier
//   phase 2: point p = weighted gather-mean + fc chain -> out
__global__ __launch_bounds__(256, 2) void kall(
    const void* in0, const void* in1, const void* in2, const void* in3,
    const void* in4, const void* in5, const void* in6, const void* in7,
    const void* in8, const void* in9, const void* in10, const void* in11,
    const void* in12, const void* in13, const void* in14, const void* in15,
    const void* in16, const void* in17, const void* in18, const void* in19,
    const void* in20, void* outv)
{
  __shared__ __align__(16) float sm[1504];
  __shared__ float s_wsum[4];
  __shared__ int sflag;
  const int tid = threadIdx.x;
  const int b = blockIdx.x;

  // ---------------- phase 0: detect + convert ----------------
  if (tid < 64){
    const us* u = (const us*)in0;
    int cnt = 0;
    #pragma unroll
    for (int j = 0; j < 8; ++j){
      us v = u[2*(tid*8+j)];          // even us-index: fp32 low-halves if fp32
      int e = (v >> 7) & 0xff;
      cnt += (e >= 143);              // |x| >= 2^16 as bf16: impossible for real data
    }
    #pragma unroll
    for (int off = 32; off; off >>= 1) cnt += __shfl_xor(cnt, off);
    if (tid == 0) sflag = (cnt > 16);
  }
  if (b == 0 && tid == 0){ g_sumA = 0.f; g_sumB = 0.f; }
  __syncthreads();
  const int isf32 = sflag;
  {
    const int g0 = b*256 + tid;
    const int gs = NBLK*256;
    #define CVT(src, dst, n) \
      for (int i = g0; i < (n); i += gs) \
        dst[i] = isf32 ? ((const float*)(src))[i] : b2f(((const us*)(src))[i]);
    CVT(in0,  g_imf, 16000)
    CVT(in1,  g_c,   1500)
    CVT(in2,  g_ct,  1500)
    CVT(in3,  g_wc1, 2048)
    CVT(in4,  g_bc1, 64)
    CVT(in5,  g_wc2, 8192)
    CVT(in6,  g_bc2, 128)
    CVT(in7,  g_wps1,32768)
    CVT(in8,  g_bps1,256)
    CVT(in9,  g_wps2,32768)
    CVT(in10, g_bps2,128)
    CVT(in11, g_wp1, 192)
    CVT(in12, g_bp1, 64)
    CVT(in13, g_wp2, 8192)
    CVT(in14, g_bp2, 128)
    CVT(in15, g_wfc1,16384)
    CVT(in16, g_bfc1,64)
    CVT(in17, g_wfc2,10240)
    CVT(in18, g_bfc2,64)
    CVT(in19, g_wfc, 8192)
    CVT(in20, g_bfc, 64)
    #undef CVT
  }

  grid_barrier();

  // ---------------- phase 1 (grid-stride over 500 items) ----------------
  for (int item = b; item < 500; item += NBLK){
    __syncthreads();   // protect sm reuse across sequential items
    if (item < 250) {
      // KNN: 1 query per wave, 4 per item; indices + exp(-dist) + denom partials
      const int dir = (item >= 125);         // 0: query=c, ref=ct ; 1: query=ct, ref=c
      const float* refp = dir ? g_c : g_ct;
      const float* qp   = dir ? g_ct : g_c;
      int* outp = dir ? g_inds_tc : g_inds;
      float* logp = dir ? g_logB : g_logA;
      for (int e = tid; e < 1500; e += 256) sm[e] = refp[e];
      __syncthreads();
      const int lane = tid & 63;
      const int wv = tid >> 6;
      const int q = item*4 + wv;
      const int qi = q - (dir ? 500 : 0);
      float qx = qp[qi*3+0], qy = qp[qi*3+1], qz = qp[qi*3+2];
      // exact numpy op order: sum(q^2) - 2*dot + sum(r^2)
      float sq = __fadd_rn(__fadd_rn(__fmul_rn(qx,qx),__fmul_rn(qy,qy)),__fmul_rn(qz,qz));
      const u64 SENT = 0xFFFFFFFF00000000ull;   // sentinel carries valid idx 0
      u64 a0=SENT,a1=SENT,a2=SENT,a3=SENT,a4=SENT,a5=SENT,a6=SENT,a7=SENT;
      for (int j = lane; j < NN; j += 64){
        float rx = sm[j*3+0], ry = sm[j*3+1], rz = sm[j*3+2];
        float dt = __fadd_rn(__fadd_rn(__fmul_rn(qx,rx),__fmul_rn(qy,ry)),__fmul_rn(qz,rz));
        float sr = __fadd_rn(__fadd_rn(__fmul_rn(rx,rx),__fmul_rn(ry,ry)),__fmul_rn(rz,rz));
        float d2 = __fadd_rn(__fsub_rn(sq, __fmul_rn(2.f,dt)), sr);
        u32 fb = __float_as_uint(d2);
        fb = (fb & 0x80000000u) ? ~fb : (fb | 0x80000000u);   // monotone float->uint
        u64 key = ((u64)fb << 32) | (u32)j;
        if (key < a0){ u64 t=a0; a0=key; key=t; }
        if (key < a1){ u64 t=a1; a1=key; key=t; }
        if (key < a2){ u64 t=a2; a2=key; key=t; }
        if (key < a3){ u64 t=a3; a3=key; key=t; }
        if (key < a4){ u64 t=a4; a4=key; key=t; }
        if (key < a5){ u64 t=a5; a5=key; key=t; }
        if (key < a6){ u64 t=a6; a6=key; key=t; }
        if (key < a7){ u64 t=a7; a7=key; key=t; }
      }
      float wsum = 0.f;
      #pragma unroll
      for (int r8 = 0; r8 < 8; ++r8){
        u64 m = a0;
        #pragma unroll
        for (int off = 32; off; off >>= 1){
          u64 o = __shfl_xor(m, off);
          if (o < m) m = o;
        }
        bool mine = (a0 == m);
        a0 = mine ? a1 : a0;  a1 = mine ? a2 : a1;  a2 = mine ? a3 : a2;
        a3 = mine ? a4 : a3;  a4 = mine ? a5 : a4;  a5 = mine ? a6 : a5;
        a6 = mine ? a7 : a6;  a7 = mine ? SENT : a7;
        if (lane == 0){
          int idx = (int)(m & 0xffffffffu);
          outp[qi*8 + r8] = idx;
          // softmax numerator exp(-dist), reference dist order
          float rx = sm[idx*3+0], ry = sm[idx*3+1], rz = sm[idx*3+2];
          float dx = __fsub_rn(qx,rx), dy = __fsub_rn(qy,ry), dz = __fsub_rn(qz,rz);
          float s2 = __fadd_rn(__fadd_rn(__fmul_rn(dx,dx),__fmul_rn(dy,dy)),__fmul_rn(dz,dz));
          float v = expf(-sqrtf(s2));   // in [4.5e-5,1]: shift-free safe
          logp[qi*8 + r8] = v;
          wsum += v;
        }
      }
      if (lane == 0) s_wsum[wv] = wsum;
      __syncthreads();
      if (tid == 0){
        float bs = (s_wsum[0] + s_wsum[1]) + (s_wsum[2] + s_wsum[3]);
        atomicAdd(dir ? &g_sumB : &g_sumA, bs);
      }
    } else {
      // ---------------- per-point conv chains, TWO points per item ----------------
      const int p0 = (item - 250)*2;
      float* sx  = sm;          // 8   (c columns, 4-float slot per point)
      float* sxi = sm + 8;      // 64  (imf columns, 32 per point)
      float* h1  = sm + 72;     // 128 (64 per point)
      float* hy  = sm + 200;    // 128 (64 per point)
      float* cf  = sm + 328;    // 256 (128 per point)
      float* h2  = sm + 584;    // 512 (256 per point)
      if (tid < 6){
        int pt = tid >= 3; int j = tid - 3*pt;
        sx[pt*4 + j] = g_c[(p0+pt)*3 + j];
      } else if (tid >= 32 && tid < 96){
        int t = tid - 32; int pt = t >> 5, ch = t & 31;
        sxi[pt*32 + ch] = g_imf[ch*NN + p0 + pt];
      }
      __syncthreads();
      // Phase A: h1 = lrelu(pconv1 @ x + b) for both points (t0..127)
      //          hy = lrelu(conv1 @ imf + b) for both points (t128..255)
      if (tid < 128){
        int pt = tid >> 6, r = tid & 63;
        float acc = g_bp1[r];
        acc += g_wp1[r*3+0]*sx[pt*4+0];
        acc += g_wp1[r*3+1]*sx[pt*4+1];
        acc += g_wp1[r*3+2]*sx[pt*4+2];
        h1[pt*64 + r] = lrelu(acc);
      } else {
        int t = tid - 128, pt = t >> 6, r = t & 63;
        float acc = g_bc1[r];
        const float4* wrow = (const float4*)(g_wc1 + (size_t)r*32);
        const float* hp = sxi + pt*32;
        #pragma unroll 8
        for (int c4=0; c4<8; ++c4) acc += dot4(wrow[c4], hp + c4*4);
        hy[pt*64 + r] = lrelu(acc);
      }
      __syncthreads();
      // Phase B: cf = pconv2 @ h1 + b (128 rows x 2 points)
      {
        int pt = tid >> 7, r = tid & 127;
        float acc = g_bp2[r];
        const float4* wrow = (const float4*)(g_wp2 + (size_t)r*64);
        const float* hp = h1 + pt*64;
        #pragma unroll 8
        for (int c4=0; c4<16; ++c4) acc += dot4(wrow[c4], hp + c4*4);
        cf[pt*128 + r] = acc;
        g_cfw[(size_t)(p0+pt)*128 + r] = acc;
      }
      __syncthreads();
      // Phase C: h2 = lrelu(psconv1 @ cf + b) — each thread owns one row for BOTH
      // points: one weight-row load feeds two independent FMA chains (ILP x2).
      {
        int r = tid;
        float aA = g_bps1[r];
        float aB = aA;
        const float4* wrow = (const float4*)(g_wps1 + (size_t)r*128);
        #pragma unroll 8
        for (int c4=0; c4<32; ++c4){
          float4 w = wrow[c4];
          aA += dot4(w, cf + c4*4);
          aB += dot4(w, cf + 128 + c4*4);
        }
        h2[r]       = lrelu(aA);
        h2[256 + r] = lrelu(aB);
      }
      __syncthreads();
      // Phase D+E: Z = psconv2 @ h2 + b ; Y = conv2 @ hy + b (128 rows x 2 pts)
      {
        int pt = tid >> 7, r = tid & 127;
        float acc = g_bps2[r];
        const float4* wrow = (const float4*)(g_wps2 + (size_t)r*256);
        const float* hp = h2 + pt*256;
        #pragma unroll 8
        for (int c4=0; c4<64; ++c4) acc += dot4(wrow[c4], hp + c4*4);
        g_Zw[(size_t)(p0+pt)*128 + r] = acc;
        float ay = g_bc2[r];
        const float4* wy = (const float4*)(g_wc2 + (size_t)r*64);
        const float* hyp = hy + pt*64;
        #pragma unroll 8
        for (int c4=0; c4<16; ++c4) ay += dot4(wy[c4], hyp + c4*4);
        g_Yw[(size_t)(p0+pt)*128 + r] = ay;
      }
    }
  }

  grid_barrier();

  // ---------------- phase 2: gather-mean + fc chain (grid-stride points) ------
  for (int p = b; p < NN; p += NBLK){
    __syncthreads();   // protect sm reuse across sequential points
    float* sb1 = sm;          // 256 : [sf | cf]
    float* sb2 = sm + 256;    // 160 : [sfp | imf]
    float* sg  = sm + 416;    // 128 : lrelu([f2 ; f1])
    float* swa = sm + 544;    // 8
    float* swb = sm + 552;    // 8
    int* sia = (int*)(sm + 560);  // 8
    int* sib = (int*)(sm + 568);  // 8
    if (tid < 8){
      sia[tid] = clampi(g_inds[p*8 + tid]);
      sib[tid] = clampi(g_inds_tc[p*8 + tid]);
      float totA = g_sumA, totB = g_sumB;   // precomputed in phase 1
      swa[tid] = g_logA[p*8 + tid] / totA;
      swb[tid] = g_logB[p*8 + tid] / totB;
    }
    if (tid >= 64 && tid < 192)  sb1[128 + (tid-64)]  = g_cfw[(size_t)p*128 + (tid-64)];
    if (tid >= 192 && tid < 224) sb2[128 + (tid-192)] = g_imf[(tid-192)*NN + p];
    __syncthreads();
    // gather-mean: t0..127 -> sf (from Y), t128..255 -> sfp (from Z)
    if (tid < 128){
      int r = tid;
      float acc = 0.f;
      #pragma unroll
      for (int j=0;j<8;++j) acc += swa[j] * g_Yw[(size_t)sia[j]*128 + r];
      sb1[r] = acc * 0.125f;
    } else {
      int r = tid - 128;
      float acc = 0.f;
      #pragma unroll
      for (int j=0;j<8;++j) acc += swb[j] * g_Zw[(size_t)sib[j]*128 + r];
      sb2[r] = acc * 0.125f;
    }
    __syncthreads();
    // f1 (t0..63, dot256) ; f2 (t64..127, dot160); g = lrelu([f2 ; f1])
    if (tid < 64){
      int r = tid;
      float a1 = g_bfc1[r];
      const float4* w1 = (const float4*)(g_wfc1 + (size_t)r*256);
      #pragma unroll 8
      for (int c4=0; c4<64; ++c4) a1 += dot4(w1[c4], sb1 + c4*4);
      sg[64 + r] = lrelu(a1);
    } else if (tid < 128){
      int r = tid - 64;
      float a2 = g_bfc2[r];
      const float4* w2 = (const float4*)(g_wfc2 + (size_t)r*160);
      #pragma unroll 8
      for (int c4=0; c4<40; ++c4) a2 += dot4(w2[c4], sb2 + c4*4);
      sg[r] = lrelu(a2);
    }
    __syncthreads();
    // out = wfc @ g + b (t0..63, dot128)
    if (tid < 64){
      int r = tid;
      float a = g_bfc[r];
      const float4* w3 = (const float4*)(g_wfc + (size_t)r*128);
      #pragma unroll 8
      for (int c4=0; c4<32; ++c4) a += dot4(w3[c4], sg + c4*4);
      if (isf32) ((float*)outv)[r*NN + p] = a;
      else       ((us*)outv)[r*NN + p] = f2b(a);
    }
  }
}

extern "C" void kernel_launch(void* const* d_in, const int* in_sizes, int n_in,
                              void* d_out, int out_size, void* d_ws, size_t ws_size,
                              hipStream_t stream)
{
  (void)d_ws; (void)ws_size; (void)in_sizes; (void)n_in; (void)out_size;
  kall<<<NBLK, 256, 0, stream>>>(
    d_in[0], d_in[1], d_in[2], d_in[3], d_in[4], d_in[5], d_in[6],
    d_in[7], d_in[8], d_in[9], d_in[10], d_in[11], d_in[12], d_in[13],
    d_in[14], d_in[15], d_in[16], d_in[17], d_in[18], d_in[19], d_in[20],
    d_out);
}